// Round 5
// baseline (273.631 us; speedup 1.0000x reference)
//
#include <hip/hip_runtime.h>

#define D 128
#define TILE 64                // rows per block-iteration (4 waves x 16 rows)

typedef float fx4 __attribute__((ext_vector_type(4)));

// Wave-contiguous layout: wave w owns a 16-row window per tile; lanes 0-31
// take even rows, lanes 32-63 odd rows, so each x-load instruction covers
// rows 2k,2k+1 = 1KB contiguous. 8 independent 1KB loads in flight per wave
// per tile. Sorted batch ids -> branch-free fast path; per-group register
// accumulator flushes via atomicAdd only on segment change.
__global__ __launch_bounds__(256)
void WeightedSum_kernel(const float* __restrict__ x,
                        const int* __restrict__ batch,
                        const float* __restrict__ mask,
                        const float* __restrict__ W,
                        const float* __restrict__ bptr,
                        float* __restrict__ out,
                        int N, int rowsPerBlock)
{
    const int tid  = threadIdx.x;
    const int wid  = tid >> 6;          // wave 0..3
    const int par  = (tid >> 5) & 1;    // 0 = even rows, 1 = odd rows
    const int lane = tid & 31;
    const int c0   = lane * 4;

    const float4 wv  = *reinterpret_cast<const float4*>(W + c0);
    const float bias = bptr[0];

    const int rowStart = blockIdx.x * rowsPerBlock;
    if (rowStart >= N) return;
    const int rowEnd = min(rowStart + rowsPerBlock, N);

    const fx4*    __restrict__ x4 = reinterpret_cast<const fx4*>(x);
    const int4*   __restrict__ b4 = reinterpret_cast<const int4*>(batch);
    const float4* __restrict__ m4 = reinterpret_cast<const float4*>(mask);

    float4 acc = make_float4(0.f, 0.f, 0.f, 0.f);
    int cur = -1;

    auto flush = [&](int seg) {
        float* o = out + (size_t)seg * D + c0;
        atomicAdd(o + 0, acc.x);
        atomicAdd(o + 1, acc.y);
        atomicAdd(o + 2, acc.z);
        atomicAdd(o + 3, acc.w);
        acc = make_float4(0.f, 0.f, 0.f, 0.f);
    };

    const int span = rowEnd - rowStart;
    const int nT   = span / TILE;

    for (int t = 0; t < nT; ++t) {
        const int wb = rowStart + t * TILE + wid * 16;   // wave's 16-row window

        // metadata: 4x int4 + 4x float4, same addresses across the wave
        const int4   i0 = b4[(wb >> 2) + 0], i1 = b4[(wb >> 2) + 1];
        const int4   i2 = b4[(wb >> 2) + 2], i3 = b4[(wb >> 2) + 3];
        const float4 q0 = m4[(wb >> 2) + 0], q1 = m4[(wb >> 2) + 1];
        const float4 q2 = m4[(wb >> 2) + 2], q3 = m4[(wb >> 2) + 3];

        // 8 x-loads; each wave instruction = rows 2k,2k+1 = 1KB contiguous
        fx4 xk[8];
        const size_t rb = (size_t)(wb + par) * (D / 4) + lane;
        #pragma unroll
        for (int k = 0; k < 8; ++k)
            xk[k] = x4[rb + (size_t)(2 * k) * (D / 4)];

        // per-parity metadata, compile-time indexed (no scratch)
        const int   ide[8] = { i0.x, i0.z, i1.x, i1.z, i2.x, i2.z, i3.x, i3.z };
        const int   ido[8] = { i0.y, i0.w, i1.y, i1.w, i2.y, i2.w, i3.y, i3.w };
        const float qe[8]  = { q0.x, q0.z, q1.x, q1.z, q2.x, q2.z, q3.x, q3.z };
        const float qo[8]  = { q0.y, q0.w, q1.y, q1.w, q2.y, q2.w, q3.y, q3.w };

        float pd[8];
        #pragma unroll
        for (int k = 0; k < 8; ++k)
            pd[k] = xk[k].x * wv.x + xk[k].y * wv.y + xk[k].z * wv.z + xk[k].w * wv.w;

        #pragma unroll
        for (int off = 16; off >= 1; off >>= 1) {     // 8 independent chains
            #pragma unroll
            for (int k = 0; k < 8; ++k)
                pd[k] += __shfl_xor(pd[k], off, 32);
        }

        float wk[8];
        #pragma unroll
        for (int k = 0; k < 8; ++k) {
            const float m = par ? qo[k] : qe[k];
            wk[k] = (1.0f / (1.0f + __expf(-(pd[k] + bias)))) * m;
        }

        const int idFirst = par ? ido[0] : ide[0];
        const int idLast  = par ? ido[7] : ide[7];

        if (idFirst == cur && idLast == cur) {
            // fast path: all 8 rows in the current segment (sorted ids)
            #pragma unroll
            for (int k = 0; k < 8; ++k) {
                acc.x += wk[k] * xk[k].x;
                acc.y += wk[k] * xk[k].y;
                acc.z += wk[k] * xk[k].z;
                acc.w += wk[k] * xk[k].w;
            }
        } else {
            #pragma unroll
            for (int k = 0; k < 8; ++k) {
                const int id = par ? ido[k] : ide[k];
                if (id != cur) {
                    if (cur >= 0) flush(cur);
                    cur = id;
                }
                acc.x += wk[k] * xk[k].x;
                acc.y += wk[k] * xk[k].y;
                acc.z += wk[k] * xk[k].z;
                acc.w += wk[k] * xk[k].w;
            }
        }
    }

    // tail rows (span not a multiple of TILE): strided per-group walk
    {
        const int grp = tid >> 5;
        for (int row = rowStart + nT * TILE + grp; row < rowEnd; row += 8) {
            const int s = batch[row];
            if (s != cur) {
                if (cur >= 0) flush(cur);
                cur = s;
            }
            const fx4 xv = x4[(size_t)row * (D / 4) + lane];
            const float m = mask[row];
            float pd = xv.x * wv.x + xv.y * wv.y + xv.z * wv.z + xv.w * wv.w;
            #pragma unroll
            for (int off = 16; off >= 1; off >>= 1)
                pd += __shfl_xor(pd, off, 32);
            const float wgt = (1.0f / (1.0f + __expf(-(pd + bias)))) * m;
            acc.x += wgt * xv.x;
            acc.y += wgt * xv.y;
            acc.z += wgt * xv.z;
            acc.w += wgt * xv.w;
        }
    }

    if (cur >= 0) flush(cur);
}

extern "C" void kernel_launch(void* const* d_in, const int* in_sizes, int n_in,
                              void* d_out, int out_size, void* d_ws, size_t ws_size,
                              hipStream_t stream)
{
    const float* x     = (const float*)d_in[0];
    const int*   batch = (const int*)d_in[1];
    const float* mask  = (const float*)d_in[2];
    const float* W     = (const float*)d_in[3];
    const float* b     = (const float*)d_in[4];

    float* out = (float*)d_out;
    const int N = in_sizes[1];

    // atomically accumulated -> zero first (harness poisons with 0xAA)
    (void)hipMemsetAsync(d_out, 0, (size_t)out_size * sizeof(float), stream);

    const int nBlocks = 4096;
    // multiple of TILE so tiles stay aligned; tail loop covers any remainder
    const int rowsPerBlock = (((N + nBlocks - 1) / nBlocks) + TILE - 1) & ~(TILE - 1);

    WeightedSum_kernel<<<nBlocks, 256, 0, stream>>>(x, batch, mask, W, b, out,
                                                    N, rowsPerBlock);
}

// Round 6
// 200.318 us; speedup vs baseline: 1.3660x; 1.3660x over previous
//
#include <hip/hip_runtime.h>

#define D 128
#define GPB 8                   // 32-lane groups per 256-thread block
#define PACK 8                  // consecutive rows per group-iteration
#define BLKROWS (GPB * PACK)    // rowsPerBlock must be a multiple of 64

typedef float fx4 __attribute__((ext_vector_type(4)));

// Blocked partition: each 32-lane group owns a CONTIGUOUS sub-chunk of
// rowsPerBlock/8 rows (128 < avg segment of 244), so most groups cross at
// most 1-2 segment boundaries -> ~2.5x fewer atomic flushes than the
// interleaved mapping, and far less aliasing on output cachelines.
// Per iteration a group issues 8 independent 512B row loads + 2x int4 +
// 2x float4 metadata loads. Sorted batch ids -> branch-free fast path.
__global__ __launch_bounds__(256)
void WeightedSum_kernel(const float* __restrict__ x,
                        const int* __restrict__ batch,
                        const float* __restrict__ mask,
                        const float* __restrict__ W,
                        const float* __restrict__ bptr,
                        float* __restrict__ out,
                        int N, int rowsPerBlock)
{
    const int tid  = threadIdx.x;
    const int lane = tid & 31;
    const int grp  = tid >> 5;
    const int c0   = lane * 4;

    const float4 wv  = *reinterpret_cast<const float4*>(W + c0);
    const float bias = bptr[0];

    const int rowStart = blockIdx.x * rowsPerBlock;
    if (rowStart >= N) return;
    const int rowEnd = min(rowStart + rowsPerBlock, N);
    const int sub = rowsPerBlock / GPB;          // multiple of PACK (8)

    const int gs = rowStart + grp * sub;         // group's contiguous range
    if (gs >= rowEnd) return;                    // exec-masked per half-wave
    const int ge = min(gs + sub, rowEnd);

    const fx4*    __restrict__ x4 = reinterpret_cast<const fx4*>(x);
    const int4*   __restrict__ b4 = reinterpret_cast<const int4*>(batch);
    const float4* __restrict__ m4 = reinterpret_cast<const float4*>(mask);

    float4 acc = make_float4(0.f, 0.f, 0.f, 0.f);
    int cur = -1;

    auto flush = [&](int seg) {
        float* o = out + (size_t)seg * D + c0;
        atomicAdd(o + 0, acc.x);
        atomicAdd(o + 1, acc.y);
        atomicAdd(o + 2, acc.z);
        atomicAdd(o + 3, acc.w);
        acc = make_float4(0.f, 0.f, 0.f, 0.f);
    };

    int r = gs;
    for (; r + PACK <= ge; r += PACK) {          // gs is 8-aligned within grid
        const int4   i0 = b4[(r >> 2) + 0], i1 = b4[(r >> 2) + 1];
        const float4 q0 = m4[(r >> 2) + 0], q1 = m4[(r >> 2) + 1];

        fx4 xk[PACK];
        const size_t rb = (size_t)r * (D / 4) + lane;
        #pragma unroll
        for (int k = 0; k < PACK; ++k)
            xk[k] = __builtin_nontemporal_load(&x4[rb + (size_t)k * (D / 4)]);

        float pd[PACK];
        #pragma unroll
        for (int k = 0; k < PACK; ++k)
            pd[k] = xk[k].x * wv.x + xk[k].y * wv.y + xk[k].z * wv.z + xk[k].w * wv.w;

        #pragma unroll
        for (int off = 16; off >= 1; off >>= 1) {   // 8 independent chains
            #pragma unroll
            for (int k = 0; k < PACK; ++k)
                pd[k] += __shfl_xor(pd[k], off, 32);
        }

        const float mm[PACK] = { q0.x, q0.y, q0.z, q0.w, q1.x, q1.y, q1.z, q1.w };
        float wk[PACK];
        #pragma unroll
        for (int k = 0; k < PACK; ++k)
            wk[k] = (1.0f / (1.0f + __expf(-(pd[k] + bias)))) * mm[k];

        if (i0.x == cur && i1.w == cur) {
            // fast path: whole pack inside current segment (sorted ids)
            #pragma unroll
            for (int k = 0; k < PACK; ++k) {
                acc.x += wk[k] * xk[k].x;
                acc.y += wk[k] * xk[k].y;
                acc.z += wk[k] * xk[k].z;
                acc.w += wk[k] * xk[k].w;
            }
        } else {
            const int sv[PACK] = { i0.x, i0.y, i0.z, i0.w, i1.x, i1.y, i1.z, i1.w };
            #pragma unroll
            for (int k = 0; k < PACK; ++k) {
                if (sv[k] != cur) {
                    if (cur >= 0) flush(cur);
                    cur = sv[k];
                }
                acc.x += wk[k] * xk[k].x;
                acc.y += wk[k] * xk[k].y;
                acc.z += wk[k] * xk[k].z;
                acc.w += wk[k] * xk[k].w;
            }
        }
    }

    // scalar tail inside this group's range (last partial block only)
    for (; r < ge; ++r) {
        const int s = batch[r];
        if (s != cur) {
            if (cur >= 0) flush(cur);
            cur = s;
        }
        const fx4 xv = x4[(size_t)r * (D / 4) + lane];
        const float m = mask[r];
        float pd = xv.x * wv.x + xv.y * wv.y + xv.z * wv.z + xv.w * wv.w;
        #pragma unroll
        for (int off = 16; off >= 1; off >>= 1)
            pd += __shfl_xor(pd, off, 32);
        const float wgt = (1.0f / (1.0f + __expf(-(pd + bias)))) * m;
        acc.x += wgt * xv.x;
        acc.y += wgt * xv.y;
        acc.z += wgt * xv.z;
        acc.w += wgt * xv.w;
    }

    if (cur >= 0) flush(cur);
}

extern "C" void kernel_launch(void* const* d_in, const int* in_sizes, int n_in,
                              void* d_out, int out_size, void* d_ws, size_t ws_size,
                              hipStream_t stream)
{
    const float* x     = (const float*)d_in[0];
    const int*   batch = (const int*)d_in[1];
    const float* mask  = (const float*)d_in[2];
    const float* W     = (const float*)d_in[3];
    const float* b     = (const float*)d_in[4];

    float* out = (float*)d_out;
    const int N = in_sizes[1];

    // atomically accumulated -> zero first (harness poisons with 0xAA)
    (void)hipMemsetAsync(d_out, 0, (size_t)out_size * sizeof(float), stream);

    const int nBlocks = 2048;
    // multiple of 64 so each group's sub-chunk is 8-aligned (int4 loads)
    const int rowsPerBlock = (((N + nBlocks - 1) / nBlocks) + BLKROWS - 1) & ~(BLKROWS - 1);

    WeightedSum_kernel<<<nBlocks, 256, 0, stream>>>(x, batch, mask, W, b, out,
                                                    N, rowsPerBlock);
}

// Round 7
// 192.439 us; speedup vs baseline: 1.4219x; 1.0409x over previous
//
#include <hip/hip_runtime.h>

#define D 128
#define GPB 8                   // 32-lane groups per 256-thread block
#define PACK 8                  // consecutive rows per group-iteration
#define BLKROWS (GPB * PACK)    // rowsPerBlock must be a multiple of 64
#define NBLOCKS 2048            // multiple of 8 -> simple bijective XCD swizzle

typedef float fx4 __attribute__((ext_vector_type(4)));

// Blocked partition (R6 core, proven): each 32-lane group owns a CONTIGUOUS
// 128-row sub-chunk (< avg segment of 244), so most groups cross <=1-2
// segment boundaries -> ~3M atomic dwords total.
// R7 deltas: (1) plain loads (nontemporal dropped — reference 6.3 TB/s copy
// uses plain loads); (2) XCD-chunked block swizzle: adjacent blocks share
// boundary segments + contiguous x rows, so keep them on the same XCD's L2;
// each XCD then RMWs a ~disjoint slice of out.
__global__ __launch_bounds__(256)
void WeightedSum_kernel(const float* __restrict__ x,
                        const int* __restrict__ batch,
                        const float* __restrict__ mask,
                        const float* __restrict__ W,
                        const float* __restrict__ bptr,
                        float* __restrict__ out,
                        int N, int rowsPerBlock)
{
    const int tid  = threadIdx.x;
    const int lane = tid & 31;
    const int grp  = tid >> 5;
    const int c0   = lane * 4;

    const float4 wv  = *reinterpret_cast<const float4*>(W + c0);
    const float bias = bptr[0];

    // bijective XCD-chunked swizzle (NBLOCKS % 8 == 0): XCD k gets the
    // contiguous block range [k*NBLOCKS/8, (k+1)*NBLOCKS/8).
    const int bid = (int)blockIdx.x;
    const int wg  = (bid & 7) * (NBLOCKS / 8) + (bid >> 3);

    const int rowStart = wg * rowsPerBlock;
    if (rowStart >= N) return;
    const int rowEnd = min(rowStart + rowsPerBlock, N);
    const int sub = rowsPerBlock / GPB;          // multiple of PACK (8)

    const int gs = rowStart + grp * sub;         // group's contiguous range
    if (gs >= rowEnd) return;
    const int ge = min(gs + sub, rowEnd);

    const fx4*    __restrict__ x4 = reinterpret_cast<const fx4*>(x);
    const int4*   __restrict__ b4 = reinterpret_cast<const int4*>(batch);
    const float4* __restrict__ m4 = reinterpret_cast<const float4*>(mask);

    float4 acc = make_float4(0.f, 0.f, 0.f, 0.f);
    int cur = -1;

    auto flush = [&](int seg) {
        float* o = out + (size_t)seg * D + c0;
        atomicAdd(o + 0, acc.x);
        atomicAdd(o + 1, acc.y);
        atomicAdd(o + 2, acc.z);
        atomicAdd(o + 3, acc.w);
        acc = make_float4(0.f, 0.f, 0.f, 0.f);
    };

    int r = gs;
    for (; r + PACK <= ge; r += PACK) {
        const int4   i0 = b4[(r >> 2) + 0], i1 = b4[(r >> 2) + 1];
        const float4 q0 = m4[(r >> 2) + 0], q1 = m4[(r >> 2) + 1];

        fx4 xk[PACK];
        const size_t rb = (size_t)r * (D / 4) + lane;
        #pragma unroll
        for (int k = 0; k < PACK; ++k)
            xk[k] = x4[rb + (size_t)k * (D / 4)];

        float pd[PACK];
        #pragma unroll
        for (int k = 0; k < PACK; ++k)
            pd[k] = xk[k].x * wv.x + xk[k].y * wv.y + xk[k].z * wv.z + xk[k].w * wv.w;

        #pragma unroll
        for (int off = 16; off >= 1; off >>= 1) {   // 8 independent chains
            #pragma unroll
            for (int k = 0; k < PACK; ++k)
                pd[k] += __shfl_xor(pd[k], off, 32);
        }

        const float mm[PACK] = { q0.x, q0.y, q0.z, q0.w, q1.x, q1.y, q1.z, q1.w };
        float wk[PACK];
        #pragma unroll
        for (int k = 0; k < PACK; ++k)
            wk[k] = (1.0f / (1.0f + __expf(-(pd[k] + bias)))) * mm[k];

        if (i0.x == cur && i1.w == cur) {
            // fast path: whole pack inside current segment (sorted ids)
            #pragma unroll
            for (int k = 0; k < PACK; ++k) {
                acc.x += wk[k] * xk[k].x;
                acc.y += wk[k] * xk[k].y;
                acc.z += wk[k] * xk[k].z;
                acc.w += wk[k] * xk[k].w;
            }
        } else {
            const int sv[PACK] = { i0.x, i0.y, i0.z, i0.w, i1.x, i1.y, i1.z, i1.w };
            #pragma unroll
            for (int k = 0; k < PACK; ++k) {
                if (sv[k] != cur) {
                    if (cur >= 0) flush(cur);
                    cur = sv[k];
                }
                acc.x += wk[k] * xk[k].x;
                acc.y += wk[k] * xk[k].y;
                acc.z += wk[k] * xk[k].z;
                acc.w += wk[k] * xk[k].w;
            }
        }
    }

    // scalar tail inside this group's range (last partial block only)
    for (; r < ge; ++r) {
        const int s = batch[r];
        if (s != cur) {
            if (cur >= 0) flush(cur);
            cur = s;
        }
        const fx4 xv = x4[(size_t)r * (D / 4) + lane];
        const float m = mask[r];
        float pd = xv.x * wv.x + xv.y * wv.y + xv.z * wv.z + xv.w * wv.w;
        #pragma unroll
        for (int off = 16; off >= 1; off >>= 1)
            pd += __shfl_xor(pd, off, 32);
        const float wgt = (1.0f / (1.0f + __expf(-(pd + bias)))) * m;
        acc.x += wgt * xv.x;
        acc.y += wgt * xv.y;
        acc.z += wgt * xv.z;
        acc.w += wgt * xv.w;
    }

    if (cur >= 0) flush(cur);
}

extern "C" void kernel_launch(void* const* d_in, const int* in_sizes, int n_in,
                              void* d_out, int out_size, void* d_ws, size_t ws_size,
                              hipStream_t stream)
{
    const float* x     = (const float*)d_in[0];
    const int*   batch = (const int*)d_in[1];
    const float* mask  = (const float*)d_in[2];
    const float* W     = (const float*)d_in[3];
    const float* b     = (const float*)d_in[4];

    float* out = (float*)d_out;
    const int N = in_sizes[1];

    // atomically accumulated -> zero first (harness poisons with 0xAA)
    (void)hipMemsetAsync(d_out, 0, (size_t)out_size * sizeof(float), stream);

    // multiple of 64 so each group's sub-chunk is 8-aligned (int4 loads)
    const int rowsPerBlock = (((N + NBLOCKS - 1) / NBLOCKS) + BLKROWS - 1) & ~(BLKROWS - 1);

    WeightedSum_kernel<<<NBLOCKS, 256, 0, stream>>>(x, batch, mask, W, b, out,
                                                    N, rowsPerBlock);
}

// Round 8
// 191.052 us; speedup vs baseline: 1.4322x; 1.0073x over previous
//
#include <hip/hip_runtime.h>

#define D 128
#define GPB 8                   // 32-lane groups per 256-thread block
#define PACK 8                  // consecutive rows per group-iteration
#define BLKROWS (GPB * PACK)    // rowsPerBlock must be a multiple of 64
#define NBLOCKS 2048            // multiple of 8 -> bijective XCD swizzle

typedef float fx4 __attribute__((ext_vector_type(4)));

// R7 core (blocked partition + XCD-chunked swizzle) with a multi-value
// tree reduction: the 8 row-dots share one exchange network
// (16 shuffles/pack instead of 40) and ONE sigmoid per lane instead of 8.
__global__ __launch_bounds__(256)
void WeightedSum_kernel(const float* __restrict__ x,
                        const int* __restrict__ batch,
                        const float* __restrict__ mask,
                        const float* __restrict__ W,
                        const float* __restrict__ bptr,
                        float* __restrict__ out,
                        int N, int rowsPerBlock)
{
    const int tid  = threadIdx.x;
    const int lane = tid & 31;
    const int grp  = tid >> 5;
    const int c0   = lane * 4;

    const float4 wv  = *reinterpret_cast<const float4*>(W + c0);
    const float bias = bptr[0];

    const int bid = (int)blockIdx.x;
    const int wg  = (bid & 7) * (NBLOCKS / 8) + (bid >> 3);

    const int rowStart = wg * rowsPerBlock;
    if (rowStart >= N) return;
    const int rowEnd = min(rowStart + rowsPerBlock, N);
    const int sub = rowsPerBlock / GPB;

    const int gs = rowStart + grp * sub;
    if (gs >= rowEnd) return;
    const int ge = min(gs + sub, rowEnd);

    const fx4*    __restrict__ x4 = reinterpret_cast<const fx4*>(x);
    const int4*   __restrict__ b4 = reinterpret_cast<const int4*>(batch);
    const float4* __restrict__ m4 = reinterpret_cast<const float4*>(mask);

    const bool b0 = (lane & 1) != 0;
    const bool b1 = (lane & 2) != 0;
    const bool b2 = (lane & 4) != 0;

    float4 acc = make_float4(0.f, 0.f, 0.f, 0.f);
    int cur = -1;

    auto flush = [&](int seg) {
        float* o = out + (size_t)seg * D + c0;
        atomicAdd(o + 0, acc.x);
        atomicAdd(o + 1, acc.y);
        atomicAdd(o + 2, acc.z);
        atomicAdd(o + 3, acc.w);
        acc = make_float4(0.f, 0.f, 0.f, 0.f);
    };

    int r = gs;
    for (; r + PACK <= ge; r += PACK) {
        const int4   i0 = b4[(r >> 2) + 0], i1 = b4[(r >> 2) + 1];
        const float4 q0 = m4[(r >> 2) + 0], q1 = m4[(r >> 2) + 1];

        fx4 xk[PACK];
        const size_t rb = (size_t)r * (D / 4) + lane;
        #pragma unroll
        for (int k = 0; k < PACK; ++k)
            xk[k] = x4[rb + (size_t)k * (D / 4)];

        float pd[PACK];
        #pragma unroll
        for (int k = 0; k < PACK; ++k)
            pd[k] = xk[k].x * wv.x + xk[k].y * wv.y + xk[k].z * wv.z + xk[k].w * wv.w;

        // ---- multi-value tree reduce: 8 rows share one exchange network.
        // step m=1: 8 -> 4 values; v4[j] = pair-sum of row 4*b0 + j
        float v4[4];
        #pragma unroll
        for (int j = 0; j < 4; ++j) {
            const float send = b0 ? pd[j] : pd[j + 4];
            const float keep = b0 ? pd[j + 4] : pd[j];
            v4[j] = keep + __shfl_xor(send, 1, 32);
        }
        // step m=2: 4 -> 2; v2[j] = quad-sum of row 4*b0 + 2*b1 + j
        float v2[2];
        #pragma unroll
        for (int j = 0; j < 2; ++j) {
            const float send = b1 ? v4[j] : v4[j + 2];
            const float keep = b1 ? v4[j + 2] : v4[j];
            v2[j] = keep + __shfl_xor(send, 2, 32);
        }
        // step m=4: 2 -> 1; v1 = octet-sum of row rho = 4*b0 + 2*b1 + b2
        float v1;
        {
            const float send = b2 ? v2[0] : v2[1];
            const float keep = b2 ? v2[1] : v2[0];
            v1 = keep + __shfl_xor(send, 4, 32);
        }
        // finish across the 4 octets
        v1 += __shfl_xor(v1, 8, 32);
        v1 += __shfl_xor(v1, 16, 32);

        // ONE sigmoid per lane (for row rho(lane)); mask applied after bcast
        const float sig = 1.0f / (1.0f + __expf(-(v1 + bias)));

        // ---- inverse network: broadcast the 8 sigmoids back, row-ordered
        float w8[PACK];
        {
            const float o4 = __shfl_xor(sig, 4, 32);
            const float wb2_0 = b2 ? o4 : sig;    // row 4b0+2b1+0
            const float wb2_1 = b2 ? sig : o4;    // row 4b0+2b1+1
            const float o2a = __shfl_xor(wb2_0, 2, 32);
            const float o2b = __shfl_xor(wb2_1, 2, 32);
            const float wA = b1 ? o2a : wb2_0;    // row 4b0+0
            const float wB = b1 ? o2b : wb2_1;    // row 4b0+1
            const float wC = b1 ? wb2_0 : o2a;    // row 4b0+2
            const float wD = b1 ? wb2_1 : o2b;    // row 4b0+3
            const float oA = __shfl_xor(wA, 1, 32);
            const float oB = __shfl_xor(wB, 1, 32);
            const float oC = __shfl_xor(wC, 1, 32);
            const float oD = __shfl_xor(wD, 1, 32);
            w8[0] = b0 ? oA : wA;
            w8[1] = b0 ? oB : wB;
            w8[2] = b0 ? oC : wC;
            w8[3] = b0 ? oD : wD;
            w8[4] = b0 ? wA : oA;
            w8[5] = b0 ? wB : oB;
            w8[6] = b0 ? wC : oC;
            w8[7] = b0 ? wD : oD;
        }

        const float mm[PACK] = { q0.x, q0.y, q0.z, q0.w, q1.x, q1.y, q1.z, q1.w };
        float wk[PACK];
        #pragma unroll
        for (int k = 0; k < PACK; ++k)
            wk[k] = w8[k] * mm[k];

        if (i0.x == cur && i1.w == cur) {
            // fast path: whole pack inside current segment (sorted ids)
            #pragma unroll
            for (int k = 0; k < PACK; ++k) {
                acc.x += wk[k] * xk[k].x;
                acc.y += wk[k] * xk[k].y;
                acc.z += wk[k] * xk[k].z;
                acc.w += wk[k] * xk[k].w;
            }
        } else {
            const int sv[PACK] = { i0.x, i0.y, i0.z, i0.w, i1.x, i1.y, i1.z, i1.w };
            #pragma unroll
            for (int k = 0; k < PACK; ++k) {
                if (sv[k] != cur) {
                    if (cur >= 0) flush(cur);
                    cur = sv[k];
                }
                acc.x += wk[k] * xk[k].x;
                acc.y += wk[k] * xk[k].y;
                acc.z += wk[k] * xk[k].z;
                acc.w += wk[k] * xk[k].w;
            }
        }
    }

    // scalar tail inside this group's range (last partial block only)
    for (; r < ge; ++r) {
        const int s = batch[r];
        if (s != cur) {
            if (cur >= 0) flush(cur);
            cur = s;
        }
        const fx4 xv = x4[(size_t)r * (D / 4) + lane];
        const float m = mask[r];
        float pd = xv.x * wv.x + xv.y * wv.y + xv.z * wv.z + xv.w * wv.w;
        #pragma unroll
        for (int off = 16; off >= 1; off >>= 1)
            pd += __shfl_xor(pd, off, 32);
        const float wgt = (1.0f / (1.0f + __expf(-(pd + bias)))) * m;
        acc.x += wgt * xv.x;
        acc.y += wgt * xv.y;
        acc.z += wgt * xv.z;
        acc.w += wgt * xv.w;
    }

    if (cur >= 0) flush(cur);
}

extern "C" void kernel_launch(void* const* d_in, const int* in_sizes, int n_in,
                              void* d_out, int out_size, void* d_ws, size_t ws_size,
                              hipStream_t stream)
{
    const float* x     = (const float*)d_in[0];
    const int*   batch = (const int*)d_in[1];
    const float* mask  = (const float*)d_in[2];
    const float* W     = (const float*)d_in[3];
    const float* b     = (const float*)d_in[4];

    float* out = (float*)d_out;
    const int N = in_sizes[1];

    // atomically accumulated -> zero first (harness poisons with 0xAA)
    (void)hipMemsetAsync(d_out, 0, (size_t)out_size * sizeof(float), stream);

    // multiple of 64 so each group's sub-chunk is 8-aligned (int4 loads)
    const int rowsPerBlock = (((N + NBLOCKS - 1) / NBLOCKS) + BLKROWS - 1) & ~(BLKROWS - 1);

    WeightedSum_kernel<<<NBLOCKS, 256, 0, stream>>>(x, batch, mask, W, b, out,
                                                    N, rowsPerBlock);
}